// Round 4
// baseline (454.446 us; speedup 1.0000x reference)
//
#include <hip/hip_runtime.h>

#define Mdim 8
#define Tdim 4000
#define Bdim 128
#define Hdim 512
#define NPER (Tdim*Hdim)
#define EPSG 1e-8f

typedef __attribute__((ext_vector_type(8))) short short8;
typedef __attribute__((ext_vector_type(4))) float floatx4;

static __device__ __forceinline__ float bits2f(unsigned short s) {
  union { unsigned int u; float f; } v; v.u = ((unsigned int)s) << 16; return v.f;
}
static __device__ __forceinline__ unsigned short f2bits(float f) {
  union { float f; unsigned int u; } v; v.f = f;
  unsigned int u = v.u;
  u += 0x7fffu + ((u >> 16) & 1u);   // RNE
  return (unsigned short)(u >> 16);
}
static __device__ __forceinline__ short8 pack8(const float4& a, const float4& b) {
  short8 v;
  v[0]=(short)f2bits(a.x); v[1]=(short)f2bits(a.y); v[2]=(short)f2bits(a.z); v[3]=(short)f2bits(a.w);
  v[4]=(short)f2bits(b.x); v[5]=(short)f2bits(b.y); v[6]=(short)f2bits(b.z); v[7]=(short)f2bits(b.w);
  return v;
}

// ---------------- K1: conv1 GEMM (x f32 -> bf16 MFMA) + PReLU + gLN1 partials -> Hbuf [M,T,H] bf16
__global__ __launch_bounds__(256) void k_conv1(
    const float* __restrict__ x,
    const float* __restrict__ w1,
    const float* __restrict__ a1p,
    unsigned short* __restrict__ Hbuf,
    float* __restrict__ stats1)
{
  __shared__ __align__(16) unsigned short ldsW[64*136];
  __shared__ __align__(16) unsigned short ltile[64*72];
  __shared__ float red[512];

  const int tid = threadIdx.x;
  const int t0 = blockIdx.x * 64;
  const int h0 = blockIdx.y * 64;
  const int m  = blockIdx.z;

  // stage w1 (f32) rows h0..h0+63 as bf16 into LDS
  #pragma unroll
  for (int it = 0; it < 4; ++it) {
    int idx = (it*256 + tid) * 8;
    int r = idx >> 7, c = idx & 127;
    float4 fa = *(const float4*)&w1[(size_t)(h0 + r)*Bdim + c];
    float4 fb = *(const float4*)&w1[(size_t)(h0 + r)*Bdim + c + 4];
    *(short8*)&ldsW[r*136 + c] = pack8(fa, fb);
  }

  const int lane = tid & 63, wv = tid >> 6, quad = lane >> 4, l16 = lane & 15;
  int tr = t0 + wv*16 + l16;
  int trc = tr < Tdim ? tr : Tdim-1;
  const float* xrow = x + ((size_t)m*Tdim + trc)*Bdim;
  short8 afr[4];
  #pragma unroll
  for (int ks = 0; ks < 4; ++ks) {
    float4 fa = *(const float4*)&xrow[ks*32 + quad*8];
    float4 fb = *(const float4*)&xrow[ks*32 + quad*8 + 4];
    afr[ks] = pack8(fa, fb);
  }

  floatx4 acc[4] = {};
  __syncthreads();
  #pragma unroll
  for (int ks = 0; ks < 4; ++ks) {
    #pragma unroll
    for (int nt = 0; nt < 4; ++nt) {
      short8 bfr = *(const short8*)&ldsW[(nt*16 + l16)*136 + ks*32 + quad*8];
      acc[nt] = __builtin_amdgcn_mfma_f32_16x16x32_bf16(afr[ks], bfr, acc[nt], 0, 0, 0);
    }
  }

  const float a1 = a1p[0];
  float lsum = 0.f, lss = 0.f;
  #pragma unroll
  for (int nt = 0; nt < 4; ++nt) {
    int hl = nt*16 + l16;                 // C/D: col = lane&15
    #pragma unroll
    for (int r = 0; r < 4; ++r) {
      int tl = wv*16 + quad*4 + r;        // C/D: row = quad*4+reg
      float v = acc[nt][r];
      v = v >= 0.f ? v : a1 * v;
      if (t0 + tl < Tdim) { lsum += v; lss += v*v; }
      ltile[tl*72 + hl] = f2bits(v);
    }
  }
  red[tid] = lsum; red[256 + tid] = lss;
  __syncthreads();
  // coalesced store: thread -> (row tr2 = tid>>2, 16-col chunk)
  {
    int tr2 = tid >> 2, ck = (tid & 3) * 16;
    int tg = t0 + tr2;
    if (tg < Tdim) {
      unsigned short* dst = &Hbuf[((size_t)m*Tdim + tg)*Hdim + h0 + ck];
      *(short8*)&dst[0] = *(const short8*)&ltile[tr2*72 + ck];
      *(short8*)&dst[8] = *(const short8*)&ltile[tr2*72 + ck + 8];
    }
  }
  for (int s = 128; s > 0; s >>= 1) {
    if (tid < s) { red[tid] += red[tid + s]; red[256+tid] += red[256+tid+s]; }
    __syncthreads();
  }
  if (tid == 0) {
    atomicAdd(&stats1[m*2+0], red[0]);
    atomicAdd(&stats1[m*2+1], red[256]);
  }
}

// ---------------- K2: offset branch. One wave per t; lane owns 8 contiguous channels.
__global__ __launch_bounds__(256) void k_offsets(
    const unsigned short* __restrict__ Hbuf,
    const float* __restrict__ stats1,
    const float* __restrict__ g1w,
    const float* __restrict__ b1w,
    const float* __restrict__ odw,
    const float* __restrict__ aodcp,
    const float* __restrict__ opw,
    float* __restrict__ OffAcc)
{
  const int tid = threadIdx.x, lane = tid & 63, w = tid >> 6;
  const int t = blockIdx.x*4 + w;          // grid.x = 1000 -> t < 4000 always
  const int m = blockIdx.y;
  const float invn = 1.0f/(float)NPER;
  const float mean1 = stats1[m*2]*invn;
  const float var1  = fmaxf(stats1[m*2+1]*invn - mean1*mean1, 0.f);
  const float inv1  = 1.0f/sqrtf(var1 + EPSG);
  const float aodc  = aodcp[0];

  const int c8 = lane*8;
  float g1v[8], b1v[8], wod[24], q0v[8], q1v[8], q2v[8];
  #pragma unroll
  for (int j = 0; j < 8; j += 4) {
    *(float4*)&g1v[j] = *(const float4*)&g1w[c8 + j];
    *(float4*)&b1v[j] = *(const float4*)&b1w[c8 + j];
    *(float4*)&q0v[j] = *(const float4*)&opw[c8 + j];
    *(float4*)&q1v[j] = *(const float4*)&opw[Hdim + c8 + j];
    *(float4*)&q2v[j] = *(const float4*)&opw[2*Hdim + c8 + j];
  }
  #pragma unroll
  for (int j = 0; j < 24; j += 4)
    *(float4*)&wod[j] = *(const float4*)&odw[c8*3 + j];

  const int tm1 = (t == 0) ? 1 : t-1;
  const int tp1 = (t == Tdim-1) ? Tdim-2 : t+1;
  const unsigned short* base = Hbuf + (size_t)m*Tdim*Hdim;
  short8 hm = *(const short8*)&base[(size_t)tm1*Hdim + c8];
  short8 hz = *(const short8*)&base[(size_t)t  *Hdim + c8];
  short8 hp = *(const short8*)&base[(size_t)tp1*Hdim + c8];

  float o0 = 0.f, o1 = 0.f, o2 = 0.f;
  #pragma unroll
  for (int j = 0; j < 8; ++j) {
    float A = g1v[j] * inv1;
    float C = b1v[j] - mean1*A;
    float fm = fmaf(A, bits2f((unsigned short)hm[j]), C);
    float fz = fmaf(A, bits2f((unsigned short)hz[j]), C);
    float fp = fmaf(A, bits2f((unsigned short)hp[j]), C);
    float d = fm*wod[j*3+0] + fz*wod[j*3+1] + fp*wod[j*3+2];
    d = d >= 0.f ? d : aodc*d;
    o0 = fmaf(d, q0v[j], o0);
    o1 = fmaf(d, q1v[j], o1);
    o2 = fmaf(d, q2v[j], o2);
  }
  #pragma unroll
  for (int s = 32; s > 0; s >>= 1) {
    o0 += __shfl_xor(o0, s);
    o1 += __shfl_xor(o1, s);
    o2 += __shfl_xor(o2, s);
  }
  if (lane == 0) {
    float* oa = OffAcc + ((size_t)m*Tdim + t)*3;
    oa[0] = o0; oa[1] = o1; oa[2] = o2;
  }
}

// ---------------- K3: deformable dw conv + bias + PReLU2 + gLN2 partials -> Ybuf [M,T,H] bf16
// One wave per (m,t); lane owns 8 contiguous channels -> all gathers are short8, coalesced.
__global__ __launch_bounds__(256) void k_deform(
    const unsigned short* __restrict__ Hbuf,
    const float* __restrict__ stats1,
    const float* __restrict__ OffAcc,
    const float* __restrict__ g1w,
    const float* __restrict__ b1w,
    const float* __restrict__ aopcp,
    const float* __restrict__ dww,
    const float* __restrict__ dwb,
    const float* __restrict__ a2p,
    unsigned short* __restrict__ Ybuf,
    float* __restrict__ stats2)
{
  __shared__ float rsum[4], rss[4];
  const int tid = threadIdx.x, lane = tid & 63, w = tid >> 6;
  const int t = blockIdx.x*4 + w;          // grid.x = 1000
  const int m = blockIdx.y;

  const float invn = 1.0f/(float)NPER;
  const float mean1 = stats1[m*2]*invn;
  const float var1  = fmaxf(stats1[m*2+1]*invn - mean1*mean1, 0.f);
  const float inv1  = 1.0f/sqrtf(var1 + EPSG);
  const float aopc  = aopcp[0];
  const float a2    = a2p[0];

  // wave-uniform tap params
  int I0[3], I1[3]; float G0[3], G1[3], GS[3];
  const float tf = (float)t;
  #pragma unroll
  for (int k = 0; k < 3; ++k) {
    float off = OffAcc[((size_t)m*Tdim + t)*3 + k];
    off = off >= 0.f ? off : aopc*off;
    float pos = tf + (float)(2*k) + off;
    pos = fminf(fmaxf(pos, tf), tf + 4.0f);
    int U = (int)floorf(pos);
    if (U > Tdim + 2) U = Tdim + 2;        // Lp-2
    float Uf = (float)U;
    G0[k] = fmaxf(0.f, 1.f - fabsf(Uf - pos));
    G1[k] = fmaxf(0.f, 1.f - fabsf(Uf + 1.f - pos));
    GS[k] = G0[k] + G1[k];
    int ia = U - 2; ia = ia < 0 ? -ia : ia; if (ia > Tdim-1) ia = 2*(Tdim-1) - ia;
    int ib = U - 1; ib = ib < 0 ? -ib : ib; if (ib > Tdim-1) ib = 2*(Tdim-1) - ib;
    I0[k] = ia; I1[k] = ib;
  }

  const int c8 = lane*8;
  const unsigned short* base = Hbuf + (size_t)m*Tdim*Hdim;
  short8 s0v[3], s1v[3];
  #pragma unroll
  for (int k = 0; k < 3; ++k) {
    s0v[k] = *(const short8*)&base[(size_t)I0[k]*Hdim + c8];
    s1v[k] = *(const short8*)&base[(size_t)I1[k]*Hdim + c8];
  }

  float g1v[8], b1v[8], bv[8], wd[24];
  #pragma unroll
  for (int j = 0; j < 8; j += 4) {
    *(float4*)&g1v[j] = *(const float4*)&g1w[c8 + j];
    *(float4*)&b1v[j] = *(const float4*)&b1w[c8 + j];
    *(float4*)&bv[j]  = *(const float4*)&dwb[c8 + j];
  }
  #pragma unroll
  for (int j = 0; j < 24; j += 4)
    *(float4*)&wd[j] = *(const float4*)&dww[c8*3 + j];

  float lsum = 0.f, lss = 0.f;
  short8 yv;
  #pragma unroll
  for (int j = 0; j < 8; ++j) {
    float A = g1v[j] * inv1;
    float C = b1v[j] - mean1*A;
    float w0 = wd[j*3+0], w1 = wd[j*3+1], w2 = wd[j*3+2];
    float ybase = fmaf(C, w0*GS[0] + w1*GS[1] + w2*GS[2], bv[j]);
    float t0s = fmaf(G1[0], bits2f((unsigned short)s1v[0][j]), G0[0]*bits2f((unsigned short)s0v[0][j]));
    float t1s = fmaf(G1[1], bits2f((unsigned short)s1v[1][j]), G0[1]*bits2f((unsigned short)s0v[1][j]));
    float t2s = fmaf(G1[2], bits2f((unsigned short)s1v[2][j]), G0[2]*bits2f((unsigned short)s0v[2][j]));
    float acc = w0*t0s + w1*t1s + w2*t2s;
    float y = fmaf(A, acc, ybase);
    float p = y >= 0.f ? y : a2*y;
    lsum += p; lss += p*p;
    yv[j] = (short)f2bits(p);
  }
  *(short8*)&Ybuf[((size_t)m*Tdim + t)*Hdim + c8] = yv;

  #pragma unroll
  for (int s = 32; s > 0; s >>= 1) {
    lsum += __shfl_xor(lsum, s);
    lss  += __shfl_xor(lss, s);
  }
  if (lane == 0) { rsum[w] = lsum; rss[w] = lss; }
  __syncthreads();
  if (tid == 0) {
    atomicAdd(&stats2[m*2+0], rsum[0]+rsum[1]+rsum[2]+rsum[3]);
    atomicAdd(&stats2[m*2+1], rss[0]+rss[1]+rss[2]+rss[3]);
  }
}

// ---------------- K3b: fold gLN2 into pointwise weights: W2 = A2*pw (bf16), const2 = sum C2*pw
__global__ __launch_bounds__(64) void k_w2(
    const float* __restrict__ stats2,
    const float* __restrict__ g2w,
    const float* __restrict__ b2w,
    const float* __restrict__ pww,
    unsigned short* __restrict__ W2,
    float* __restrict__ const2)
{
  const int bid = blockIdx.x;
  const int m = bid >> 7, b = bid & 127;
  const int tid = threadIdx.x;
  const float invn = 1.0f/(float)NPER;
  const float mean2 = stats2[m*2]*invn;
  const float var2  = fmaxf(stats2[m*2+1]*invn - mean2*mean2, 0.f);
  const float inv2  = 1.0f/sqrtf(var2 + EPSG);
  float csum = 0.f;
  for (int j = tid; j < Hdim; j += 64) {
    float A = g2w[j] * inv2;
    float C = b2w[j] - mean2*A;
    float wv = pww[(size_t)b*Hdim + j];
    W2[((size_t)m*Bdim + b)*Hdim + j] = f2bits(A*wv);
    csum = fmaf(C, wv, csum);
  }
  #pragma unroll
  for (int s = 32; s > 0; s >>= 1) csum += __shfl_down(csum, s);
  if (tid == 0) const2[m*Bdim + b] = csum;
}

// ---------------- K4: final GEMM Ybuf @ W2^T + const2 + residual -> out f32
__global__ __launch_bounds__(256) void k_out(
    const unsigned short* __restrict__ Ybuf,
    const unsigned short* __restrict__ W2,
    const float* __restrict__ const2,
    const float* __restrict__ x,
    float* __restrict__ out)
{
  __shared__ __align__(16) unsigned short ldsW[64*136];
  __shared__ __align__(16) float ltf[64*68];
  const int tid = threadIdx.x;
  const int t0 = blockIdx.x*64;
  const int n0 = blockIdx.y*64;
  const int m  = blockIdx.z;
  const int lane = tid & 63, wv = tid >> 6, quad = lane >> 4, l16 = lane & 15;
  int tr = t0 + wv*16 + l16;
  int trc = tr < Tdim ? tr : Tdim-1;
  const unsigned short* arow = Ybuf + ((size_t)m*Tdim + trc)*Hdim;
  floatx4 acc[4] = {};
  for (int kc = 0; kc < 4; ++kc) {
    __syncthreads();
    #pragma unroll
    for (int it = 0; it < 4; ++it) {
      int idx = (it*256 + tid)*8;
      int r = idx >> 7, c = idx & 127;
      *(short8*)&ldsW[r*136 + c] =
        *(const short8*)&W2[((size_t)m*Bdim + n0 + r)*Hdim + kc*128 + c];
    }
    __syncthreads();
    #pragma unroll
    for (int ks = 0; ks < 4; ++ks) {
      short8 afr = *(const short8*)&arow[kc*128 + ks*32 + quad*8];
      #pragma unroll
      for (int nt = 0; nt < 4; ++nt) {
        short8 bfr = *(const short8*)&ldsW[(nt*16 + l16)*136 + ks*32 + quad*8];
        acc[nt] = __builtin_amdgcn_mfma_f32_16x16x32_bf16(afr, bfr, acc[nt], 0, 0, 0);
      }
    }
  }
  __syncthreads();   // ldsW reuse done; now fill transpose tile
  #pragma unroll
  for (int nt = 0; nt < 4; ++nt) {
    int bl = nt*16 + l16;
    float cb = const2[m*Bdim + n0 + bl];
    #pragma unroll
    for (int r = 0; r < 4; ++r) {
      int tl = wv*16 + quad*4 + r;
      ltf[tl*68 + bl] = acc[nt][r] + cb;
    }
  }
  __syncthreads();
  {
    int tr2 = tid >> 2, ck = (tid & 3) * 16;
    int tg = t0 + tr2;
    if (tg < Tdim) {
      const float* xr = &x[((size_t)m*Tdim + tg)*Bdim + n0 + ck];
      float* orow = &out[((size_t)m*Tdim + tg)*Bdim + n0 + ck];
      #pragma unroll
      for (int j = 0; j < 4; ++j) {
        float4 v = *(const float4*)&ltf[tr2*68 + ck + j*4];
        float4 rx = *(const float4*)&xr[j*4];
        v.x += rx.x; v.y += rx.y; v.z += rx.z; v.w += rx.w;
        *(float4*)&orow[j*4] = v;
      }
    }
  }
}

extern "C" void kernel_launch(void* const* d_in, const int* in_sizes, int n_in,
                              void* d_out, int out_size, void* d_ws, size_t ws_size,
                              hipStream_t stream)
{
  (void)in_sizes; (void)n_in; (void)out_size; (void)ws_size;
  const float* x    = (const float*)d_in[0];
  const float* w1   = (const float*)d_in[1];
  const float* a1   = (const float*)d_in[2];
  const float* g1   = (const float*)d_in[3];
  const float* b1   = (const float*)d_in[4];
  const float* odw  = (const float*)d_in[5];
  const float* aodc = (const float*)d_in[6];
  const float* opw  = (const float*)d_in[7];
  const float* aopc = (const float*)d_in[8];
  const float* dww  = (const float*)d_in[9];
  const float* dwb  = (const float*)d_in[10];
  const float* a2   = (const float*)d_in[11];
  const float* g2   = (const float*)d_in[12];
  const float* b2   = (const float*)d_in[13];
  const float* pww  = (const float*)d_in[14];
  float* out = (float*)d_out;

  char* ws = (char*)d_ws;
  const size_t OFF_S1 = 0;          // stats1 [M,2] f32: 64 B
  const size_t OFF_S2 = 64;         // stats2 [M,2] f32: 64 B
  const size_t OFF_C2 = 128;        // const2 [M,B] f32: 4096 B
  const size_t OFF_OF = 4224;       // OffAcc [M,T,3] f32: 384000 B
  const size_t OFF_W2 = 388224;     // W2 [M,B,H] bf16: 1048576 B
  const size_t OFF_H  = 1436800;    // Hbuf [M,T,H] bf16: 32768000 B
  const size_t OFF_Y  = 34204800;   // Ybuf [M,T,H] bf16: 32768000 B
  float* stats1 = (float*)(ws + OFF_S1);
  float* stats2 = (float*)(ws + OFF_S2);
  float* const2 = (float*)(ws + OFF_C2);
  float* OffAcc = (float*)(ws + OFF_OF);
  unsigned short* W2   = (unsigned short*)(ws + OFF_W2);
  unsigned short* Hbuf = (unsigned short*)(ws + OFF_H);
  unsigned short* Ybuf = (unsigned short*)(ws + OFF_Y);

  hipMemsetAsync(ws + OFF_S1, 0, 128, stream);  // zero stats1+stats2

  k_conv1  <<<dim3(63, 8, 8), 256, 0, stream>>>(x, w1, a1, Hbuf, stats1);
  k_offsets<<<dim3(1000, 8), 256, 0, stream>>>(Hbuf, stats1, g1, b1, odw, aodc, opw, OffAcc);
  k_deform <<<dim3(1000, 8), 256, 0, stream>>>(Hbuf, stats1, OffAcc, g1, b1, aopc, dww, dwb, a2, Ybuf, stats2);
  k_w2     <<<dim3(1024), 64, 0, stream>>>(stats2, g2, b2, pww, W2, const2);
  k_out    <<<dim3(63, 2, 8), 256, 0, stream>>>(Ybuf, W2, const2, x, out);
}

// Round 5
// 191.339 us; speedup vs baseline: 2.3751x; 2.3751x over previous
//
#include <hip/hip_runtime.h>

#define Mdim 8
#define Tdim 4000
#define Bdim 128
#define Hdim 512
#define NPER (Tdim*Hdim)
#define EPSG 1e-8f

typedef __attribute__((ext_vector_type(8))) short short8;
typedef __attribute__((ext_vector_type(4))) float floatx4;

static __device__ __forceinline__ float bits2f(unsigned short s) {
  union { unsigned int u; float f; } v; v.u = ((unsigned int)s) << 16; return v.f;
}
static __device__ __forceinline__ unsigned short f2bits(float f) {
  union { float f; unsigned int u; } v; v.f = f;
  unsigned int u = v.u;
  u += 0x7fffu + ((u >> 16) & 1u);   // RNE
  return (unsigned short)(u >> 16);
}
static __device__ __forceinline__ short8 pack8(const float4& a, const float4& b) {
  short8 v;
  v[0]=(short)f2bits(a.x); v[1]=(short)f2bits(a.y); v[2]=(short)f2bits(a.z); v[3]=(short)f2bits(a.w);
  v[4]=(short)f2bits(b.x); v[5]=(short)f2bits(b.y); v[6]=(short)f2bits(b.z); v[7]=(short)f2bits(b.w);
  return v;
}

// ---------------- generic partial-sum reduce: part[m*count + i] (float2 sum,ss) -> stats[m*2]
__global__ __launch_bounds__(256) void k_reduce(
    const float2* __restrict__ part, int count, float* __restrict__ stats)
{
  __shared__ float rs[256], rq[256];
  const int m = blockIdx.x, tid = threadIdx.x;
  float s = 0.f, q = 0.f;
  for (int i = tid; i < count; i += 256) {
    float2 p = part[(size_t)m*count + i];
    s += p.x; q += p.y;
  }
  rs[tid] = s; rq[tid] = q;
  __syncthreads();
  for (int st = 128; st > 0; st >>= 1) {
    if (tid < st) { rs[tid] += rs[tid+st]; rq[tid] += rq[tid+st]; }
    __syncthreads();
  }
  if (tid == 0) { stats[m*2] = rs[0]; stats[m*2+1] = rq[0]; }
}

// ---------------- K1: conv1 GEMM (x f32 -> bf16 MFMA) + PReLU + gLN1 partials -> Hbuf [M,T,H] bf16
__global__ __launch_bounds__(256) void k_conv1(
    const float* __restrict__ x,
    const float* __restrict__ w1,
    const float* __restrict__ a1p,
    unsigned short* __restrict__ Hbuf,
    float2* __restrict__ part1)
{
  __shared__ __align__(16) unsigned short ldsW[64*136];
  __shared__ __align__(16) unsigned short ltile[64*72];
  __shared__ float red[512];

  const int tid = threadIdx.x;
  const int t0 = blockIdx.x * 64;
  const int h0 = blockIdx.y * 64;
  const int m  = blockIdx.z;

  // stage w1 (f32) rows h0..h0+63 as bf16 into LDS
  #pragma unroll
  for (int it = 0; it < 4; ++it) {
    int idx = (it*256 + tid) * 8;
    int r = idx >> 7, c = idx & 127;
    float4 fa = *(const float4*)&w1[(size_t)(h0 + r)*Bdim + c];
    float4 fb = *(const float4*)&w1[(size_t)(h0 + r)*Bdim + c + 4];
    *(short8*)&ldsW[r*136 + c] = pack8(fa, fb);
  }

  const int lane = tid & 63, wv = tid >> 6, quad = lane >> 4, l16 = lane & 15;
  int tr = t0 + wv*16 + l16;
  int trc = tr < Tdim ? tr : Tdim-1;
  const float* xrow = x + ((size_t)m*Tdim + trc)*Bdim;
  short8 afr[4];
  #pragma unroll
  for (int ks = 0; ks < 4; ++ks) {
    float4 fa = *(const float4*)&xrow[ks*32 + quad*8];
    float4 fb = *(const float4*)&xrow[ks*32 + quad*8 + 4];
    afr[ks] = pack8(fa, fb);
  }

  floatx4 acc[4] = {};
  __syncthreads();
  #pragma unroll
  for (int ks = 0; ks < 4; ++ks) {
    #pragma unroll
    for (int nt = 0; nt < 4; ++nt) {
      short8 bfr = *(const short8*)&ldsW[(nt*16 + l16)*136 + ks*32 + quad*8];
      acc[nt] = __builtin_amdgcn_mfma_f32_16x16x32_bf16(afr[ks], bfr, acc[nt], 0, 0, 0);
    }
  }

  const float a1 = a1p[0];
  float lsum = 0.f, lss = 0.f;
  #pragma unroll
  for (int nt = 0; nt < 4; ++nt) {
    int hl = nt*16 + l16;                 // C/D: col = lane&15
    #pragma unroll
    for (int r = 0; r < 4; ++r) {
      int tl = wv*16 + quad*4 + r;        // C/D: row = quad*4+reg
      float v = acc[nt][r];
      v = v >= 0.f ? v : a1 * v;
      if (t0 + tl < Tdim) { lsum += v; lss += v*v; }
      ltile[tl*72 + hl] = f2bits(v);
    }
  }
  red[tid] = lsum; red[256 + tid] = lss;
  __syncthreads();
  // coalesced store: thread -> (row tr2 = tid>>2, 16-col chunk)
  {
    int tr2 = tid >> 2, ck = (tid & 3) * 16;
    int tg = t0 + tr2;
    if (tg < Tdim) {
      unsigned short* dst = &Hbuf[((size_t)m*Tdim + tg)*Hdim + h0 + ck];
      *(short8*)&dst[0] = *(const short8*)&ltile[tr2*72 + ck];
      *(short8*)&dst[8] = *(const short8*)&ltile[tr2*72 + ck + 8];
    }
  }
  for (int s = 128; s > 0; s >>= 1) {
    if (tid < s) { red[tid] += red[tid + s]; red[256+tid] += red[256+tid+s]; }
    __syncthreads();
  }
  if (tid == 0)
    part1[(size_t)m*504 + blockIdx.y*63 + blockIdx.x] = make_float2(red[0], red[256]);
}

// ---------------- K2: offset branch. One wave per t; lane owns 8 contiguous channels.
__global__ __launch_bounds__(256) void k_offsets(
    const unsigned short* __restrict__ Hbuf,
    const float* __restrict__ stats1,
    const float* __restrict__ g1w,
    const float* __restrict__ b1w,
    const float* __restrict__ odw,
    const float* __restrict__ aodcp,
    const float* __restrict__ opw,
    float* __restrict__ OffAcc)
{
  const int tid = threadIdx.x, lane = tid & 63, w = tid >> 6;
  const int t = blockIdx.x*4 + w;          // grid.x = 1000 -> t < 4000 always
  const int m = blockIdx.y;
  const float invn = 1.0f/(float)NPER;
  const float mean1 = stats1[m*2]*invn;
  const float var1  = fmaxf(stats1[m*2+1]*invn - mean1*mean1, 0.f);
  const float inv1  = 1.0f/sqrtf(var1 + EPSG);
  const float aodc  = aodcp[0];

  const int c8 = lane*8;
  float g1v[8], b1v[8], wod[24], q0v[8], q1v[8], q2v[8];
  #pragma unroll
  for (int j = 0; j < 8; j += 4) {
    *(float4*)&g1v[j] = *(const float4*)&g1w[c8 + j];
    *(float4*)&b1v[j] = *(const float4*)&b1w[c8 + j];
    *(float4*)&q0v[j] = *(const float4*)&opw[c8 + j];
    *(float4*)&q1v[j] = *(const float4*)&opw[Hdim + c8 + j];
    *(float4*)&q2v[j] = *(const float4*)&opw[2*Hdim + c8 + j];
  }
  #pragma unroll
  for (int j = 0; j < 24; j += 4)
    *(float4*)&wod[j] = *(const float4*)&odw[c8*3 + j];

  const int tm1 = (t == 0) ? 1 : t-1;
  const int tp1 = (t == Tdim-1) ? Tdim-2 : t+1;
  const unsigned short* base = Hbuf + (size_t)m*Tdim*Hdim;
  short8 hm = *(const short8*)&base[(size_t)tm1*Hdim + c8];
  short8 hz = *(const short8*)&base[(size_t)t  *Hdim + c8];
  short8 hp = *(const short8*)&base[(size_t)tp1*Hdim + c8];

  float o0 = 0.f, o1 = 0.f, o2 = 0.f;
  #pragma unroll
  for (int j = 0; j < 8; ++j) {
    float A = g1v[j] * inv1;
    float C = b1v[j] - mean1*A;
    float fm = fmaf(A, bits2f((unsigned short)hm[j]), C);
    float fz = fmaf(A, bits2f((unsigned short)hz[j]), C);
    float fp = fmaf(A, bits2f((unsigned short)hp[j]), C);
    float d = fm*wod[j*3+0] + fz*wod[j*3+1] + fp*wod[j*3+2];
    d = d >= 0.f ? d : aodc*d;
    o0 = fmaf(d, q0v[j], o0);
    o1 = fmaf(d, q1v[j], o1);
    o2 = fmaf(d, q2v[j], o2);
  }
  #pragma unroll
  for (int s = 32; s > 0; s >>= 1) {
    o0 += __shfl_xor(o0, s);
    o1 += __shfl_xor(o1, s);
    o2 += __shfl_xor(o2, s);
  }
  if (lane == 0) {
    float* oa = OffAcc + ((size_t)m*Tdim + t)*3;
    oa[0] = o0; oa[1] = o1; oa[2] = o2;
  }
}

// ---------------- K3: deformable dw conv + bias + PReLU2 + gLN2 partials -> Ybuf [M,T,H] bf16
__global__ __launch_bounds__(256) void k_deform(
    const unsigned short* __restrict__ Hbuf,
    const float* __restrict__ stats1,
    const float* __restrict__ OffAcc,
    const float* __restrict__ g1w,
    const float* __restrict__ b1w,
    const float* __restrict__ aopcp,
    const float* __restrict__ dww,
    const float* __restrict__ dwb,
    const float* __restrict__ a2p,
    unsigned short* __restrict__ Ybuf,
    float2* __restrict__ part2)
{
  __shared__ float rsum[4], rss[4];
  const int tid = threadIdx.x, lane = tid & 63, w = tid >> 6;
  const int t = blockIdx.x*4 + w;          // grid.x = 1000
  const int m = blockIdx.y;

  const float invn = 1.0f/(float)NPER;
  const float mean1 = stats1[m*2]*invn;
  const float var1  = fmaxf(stats1[m*2+1]*invn - mean1*mean1, 0.f);
  const float inv1  = 1.0f/sqrtf(var1 + EPSG);
  const float aopc  = aopcp[0];
  const float a2    = a2p[0];

  // wave-uniform tap params
  int I0[3], I1[3]; float G0[3], G1[3], GS[3];
  const float tf = (float)t;
  #pragma unroll
  for (int k = 0; k < 3; ++k) {
    float off = OffAcc[((size_t)m*Tdim + t)*3 + k];
    off = off >= 0.f ? off : aopc*off;
    float pos = tf + (float)(2*k) + off;
    pos = fminf(fmaxf(pos, tf), tf + 4.0f);
    int U = (int)floorf(pos);
    if (U > Tdim + 2) U = Tdim + 2;        // Lp-2
    float Uf = (float)U;
    G0[k] = fmaxf(0.f, 1.f - fabsf(Uf - pos));
    G1[k] = fmaxf(0.f, 1.f - fabsf(Uf + 1.f - pos));
    GS[k] = G0[k] + G1[k];
    int ia = U - 2; ia = ia < 0 ? -ia : ia; if (ia > Tdim-1) ia = 2*(Tdim-1) - ia;
    int ib = U - 1; ib = ib < 0 ? -ib : ib; if (ib > Tdim-1) ib = 2*(Tdim-1) - ib;
    I0[k] = ia; I1[k] = ib;
  }

  const int c8 = lane*8;
  const unsigned short* base = Hbuf + (size_t)m*Tdim*Hdim;
  short8 s0v[3], s1v[3];
  #pragma unroll
  for (int k = 0; k < 3; ++k) {
    s0v[k] = *(const short8*)&base[(size_t)I0[k]*Hdim + c8];
    s1v[k] = *(const short8*)&base[(size_t)I1[k]*Hdim + c8];
  }

  float g1v[8], b1v[8], bv[8], wd[24];
  #pragma unroll
  for (int j = 0; j < 8; j += 4) {
    *(float4*)&g1v[j] = *(const float4*)&g1w[c8 + j];
    *(float4*)&b1v[j] = *(const float4*)&b1w[c8 + j];
    *(float4*)&bv[j]  = *(const float4*)&dwb[c8 + j];
  }
  #pragma unroll
  for (int j = 0; j < 24; j += 4)
    *(float4*)&wd[j] = *(const float4*)&dww[c8*3 + j];

  float lsum = 0.f, lss = 0.f;
  short8 yv;
  #pragma unroll
  for (int j = 0; j < 8; ++j) {
    float A = g1v[j] * inv1;
    float C = b1v[j] - mean1*A;
    float w0 = wd[j*3+0], w1 = wd[j*3+1], w2 = wd[j*3+2];
    float ybase = fmaf(C, w0*GS[0] + w1*GS[1] + w2*GS[2], bv[j]);
    float t0s = fmaf(G1[0], bits2f((unsigned short)s1v[0][j]), G0[0]*bits2f((unsigned short)s0v[0][j]));
    float t1s = fmaf(G1[1], bits2f((unsigned short)s1v[1][j]), G0[1]*bits2f((unsigned short)s0v[1][j]));
    float t2s = fmaf(G1[2], bits2f((unsigned short)s1v[2][j]), G0[2]*bits2f((unsigned short)s0v[2][j]));
    float acc = w0*t0s + w1*t1s + w2*t2s;
    float y = fmaf(A, acc, ybase);
    float p = y >= 0.f ? y : a2*y;
    lsum += p; lss += p*p;
    yv[j] = (short)f2bits(p);
  }
  *(short8*)&Ybuf[((size_t)m*Tdim + t)*Hdim + c8] = yv;

  #pragma unroll
  for (int s = 32; s > 0; s >>= 1) {
    lsum += __shfl_xor(lsum, s);
    lss  += __shfl_xor(lss, s);
  }
  if (lane == 0) { rsum[w] = lsum; rss[w] = lss; }
  __syncthreads();
  if (tid == 0)
    part2[(size_t)m*1000 + blockIdx.x] =
      make_float2(rsum[0]+rsum[1]+rsum[2]+rsum[3], rss[0]+rss[1]+rss[2]+rss[3]);
}

// ---------------- K3b: fold gLN2 into pointwise weights: W2 = A2*pw (bf16), const2 = sum C2*pw
__global__ __launch_bounds__(64) void k_w2(
    const float* __restrict__ stats2,
    const float* __restrict__ g2w,
    const float* __restrict__ b2w,
    const float* __restrict__ pww,
    unsigned short* __restrict__ W2,
    float* __restrict__ const2)
{
  const int bid = blockIdx.x;
  const int m = bid >> 7, b = bid & 127;
  const int tid = threadIdx.x;
  const float invn = 1.0f/(float)NPER;
  const float mean2 = stats2[m*2]*invn;
  const float var2  = fmaxf(stats2[m*2+1]*invn - mean2*mean2, 0.f);
  const float inv2  = 1.0f/sqrtf(var2 + EPSG);
  float csum = 0.f;
  for (int j = tid; j < Hdim; j += 64) {
    float A = g2w[j] * inv2;
    float C = b2w[j] - mean2*A;
    float wv = pww[(size_t)b*Hdim + j];
    W2[((size_t)m*Bdim + b)*Hdim + j] = f2bits(A*wv);
    csum = fmaf(C, wv, csum);
  }
  #pragma unroll
  for (int s = 32; s > 0; s >>= 1) csum += __shfl_down(csum, s);
  if (tid == 0) const2[m*Bdim + b] = csum;
}

// ---------------- K4: final GEMM Ybuf @ W2^T + const2 + residual -> out f32
__global__ __launch_bounds__(256) void k_out(
    const unsigned short* __restrict__ Ybuf,
    const unsigned short* __restrict__ W2,
    const float* __restrict__ const2,
    const float* __restrict__ x,
    float* __restrict__ out)
{
  __shared__ __align__(16) unsigned short ldsW[64*136];
  __shared__ __align__(16) float ltf[64*68];
  const int tid = threadIdx.x;
  const int t0 = blockIdx.x*64;
  const int n0 = blockIdx.y*64;
  const int m  = blockIdx.z;
  const int lane = tid & 63, wv = tid >> 6, quad = lane >> 4, l16 = lane & 15;
  int tr = t0 + wv*16 + l16;
  int trc = tr < Tdim ? tr : Tdim-1;
  const unsigned short* arow = Ybuf + ((size_t)m*Tdim + trc)*Hdim;
  floatx4 acc[4] = {};
  for (int kc = 0; kc < 4; ++kc) {
    __syncthreads();
    #pragma unroll
    for (int it = 0; it < 4; ++it) {
      int idx = (it*256 + tid)*8;
      int r = idx >> 7, c = idx & 127;
      *(short8*)&ldsW[r*136 + c] =
        *(const short8*)&W2[((size_t)m*Bdim + n0 + r)*Hdim + kc*128 + c];
    }
    __syncthreads();
    #pragma unroll
    for (int ks = 0; ks < 4; ++ks) {
      short8 afr = *(const short8*)&arow[kc*128 + ks*32 + quad*8];
      #pragma unroll
      for (int nt = 0; nt < 4; ++nt) {
        short8 bfr = *(const short8*)&ldsW[(nt*16 + l16)*136 + ks*32 + quad*8];
        acc[nt] = __builtin_amdgcn_mfma_f32_16x16x32_bf16(afr, bfr, acc[nt], 0, 0, 0);
      }
    }
  }
  __syncthreads();   // ldsW reuse done; now fill transpose tile
  #pragma unroll
  for (int nt = 0; nt < 4; ++nt) {
    int bl = nt*16 + l16;
    float cb = const2[m*Bdim + n0 + bl];
    #pragma unroll
    for (int r = 0; r < 4; ++r) {
      int tl = wv*16 + quad*4 + r;
      ltf[tl*68 + bl] = acc[nt][r] + cb;
    }
  }
  __syncthreads();
  {
    int tr2 = tid >> 2, ck = (tid & 3) * 16;
    int tg = t0 + tr2;
    if (tg < Tdim) {
      const float* xr = &x[((size_t)m*Tdim + tg)*Bdim + n0 + ck];
      float* orow = &out[((size_t)m*Tdim + tg)*Bdim + n0 + ck];
      #pragma unroll
      for (int j = 0; j < 4; ++j) {
        float4 v = *(const float4*)&ltf[tr2*68 + ck + j*4];
        float4 rx = *(const float4*)&xr[j*4];
        v.x += rx.x; v.y += rx.y; v.z += rx.z; v.w += rx.w;
        *(float4*)&orow[j*4] = v;
      }
    }
  }
}

extern "C" void kernel_launch(void* const* d_in, const int* in_sizes, int n_in,
                              void* d_out, int out_size, void* d_ws, size_t ws_size,
                              hipStream_t stream)
{
  (void)in_sizes; (void)n_in; (void)out_size; (void)ws_size;
  const float* x    = (const float*)d_in[0];
  const float* w1   = (const float*)d_in[1];
  const float* a1   = (const float*)d_in[2];
  const float* g1   = (const float*)d_in[3];
  const float* b1   = (const float*)d_in[4];
  const float* odw  = (const float*)d_in[5];
  const float* aodc = (const float*)d_in[6];
  const float* opw  = (const float*)d_in[7];
  const float* aopc = (const float*)d_in[8];
  const float* dww  = (const float*)d_in[9];
  const float* dwb  = (const float*)d_in[10];
  const float* a2   = (const float*)d_in[11];
  const float* g2   = (const float*)d_in[12];
  const float* b2   = (const float*)d_in[13];
  const float* pww  = (const float*)d_in[14];
  float* out = (float*)d_out;

  char* ws = (char*)d_ws;
  const size_t OFF_S1 = 0;          // stats1 [M,2] f32: 64 B
  const size_t OFF_S2 = 64;         // stats2 [M,2] f32: 64 B
  const size_t OFF_C2 = 128;        // const2 [M,B] f32: 4096 B
  const size_t OFF_OF = 4224;       // OffAcc [M,T,3] f32: 384000 B
  const size_t OFF_P1 = 388224;     // part1 [M,504] float2: 32256 B
  const size_t OFF_P2 = 420480;     // part2 [M,1000] float2: 64000 B
  const size_t OFF_W2 = 484480;     // W2 [M,B,H] bf16: 1048576 B
  const size_t OFF_H  = 1533056;    // Hbuf [M,T,H] bf16: 32768000 B
  const size_t OFF_Y  = 34301056;   // Ybuf [M,T,H] bf16: 32768000 B
  float*  stats1 = (float*)(ws + OFF_S1);
  float*  stats2 = (float*)(ws + OFF_S2);
  float*  const2 = (float*)(ws + OFF_C2);
  float*  OffAcc = (float*)(ws + OFF_OF);
  float2* part1  = (float2*)(ws + OFF_P1);
  float2* part2  = (float2*)(ws + OFF_P2);
  unsigned short* W2   = (unsigned short*)(ws + OFF_W2);
  unsigned short* Hbuf = (unsigned short*)(ws + OFF_H);
  unsigned short* Ybuf = (unsigned short*)(ws + OFF_Y);

  k_conv1  <<<dim3(63, 8, 8), 256, 0, stream>>>(x, w1, a1, Hbuf, part1);
  k_reduce <<<dim3(8), 256, 0, stream>>>(part1, 504, stats1);
  k_offsets<<<dim3(1000, 8), 256, 0, stream>>>(Hbuf, stats1, g1, b1, odw, aodc, opw, OffAcc);
  k_deform <<<dim3(1000, 8), 256, 0, stream>>>(Hbuf, stats1, OffAcc, g1, b1, aopc, dww, dwb, a2, Ybuf, part2);
  k_reduce <<<dim3(8), 256, 0, stream>>>(part2, 1000, stats2);
  k_w2     <<<dim3(1024), 64, 0, stream>>>(stats2, g2, b2, pww, W2, const2);
  k_out    <<<dim3(63, 2, 8), 256, 0, stream>>>(Ybuf, W2, const2, x, out);
}

// Round 6
// 178.493 us; speedup vs baseline: 2.5460x; 1.0720x over previous
//
#include <hip/hip_runtime.h>

#define Mdim 8
#define Tdim 4000
#define Bdim 128
#define Hdim 512
#define NPER (Tdim*Hdim)
#define EPSG 1e-8f

typedef __attribute__((ext_vector_type(8))) short short8;
typedef __attribute__((ext_vector_type(4))) float floatx4;

static __device__ __forceinline__ float bits2f(unsigned short s) {
  union { unsigned int u; float f; } v; v.u = ((unsigned int)s) << 16; return v.f;
}
static __device__ __forceinline__ unsigned short f2bits(float f) {
  union { float f; unsigned int u; } v; v.f = f;
  unsigned int u = v.u;
  u += 0x7fffu + ((u >> 16) & 1u);   // RNE
  return (unsigned short)(u >> 16);
}
static __device__ __forceinline__ short8 pack8(const float4& a, const float4& b) {
  short8 v;
  v[0]=(short)f2bits(a.x); v[1]=(short)f2bits(a.y); v[2]=(short)f2bits(a.z); v[3]=(short)f2bits(a.w);
  v[4]=(short)f2bits(b.x); v[5]=(short)f2bits(b.y); v[6]=(short)f2bits(b.z); v[7]=(short)f2bits(b.w);
  return v;
}

// ---------------- K1: conv1 GEMM (x f32 -> bf16 MFMA) + PReLU + gLN1 partials -> Hbuf [M,T,H] bf16
// One block per (t-tile, m); loops over 8 h-chunks so the x tile is loaded/packed ONCE.
__global__ __launch_bounds__(256) void k_conv1(
    const float* __restrict__ x,
    const float* __restrict__ w1,
    const float* __restrict__ a1p,
    unsigned short* __restrict__ Hbuf,
    float2* __restrict__ part1)
{
  __shared__ __align__(16) unsigned short ldsW[64*136];
  __shared__ __align__(16) unsigned short ltile[64*72];
  __shared__ float red[512];

  const int tid = threadIdx.x;
  const int t0 = blockIdx.x * 64;
  const int m  = blockIdx.y;

  const int lane = tid & 63, wv = tid >> 6, quad = lane >> 4, l16 = lane & 15;
  int tr = t0 + wv*16 + l16;
  int trc = tr < Tdim ? tr : Tdim-1;
  const float* xrow = x + ((size_t)m*Tdim + trc)*Bdim;
  short8 afr[4];
  #pragma unroll
  for (int ks = 0; ks < 4; ++ks) {
    float4 fa = *(const float4*)&xrow[ks*32 + quad*8];
    float4 fb = *(const float4*)&xrow[ks*32 + quad*8 + 4];
    afr[ks] = pack8(fa, fb);
  }

  const float a1 = a1p[0];
  float lsum = 0.f, lss = 0.f;

  for (int hc = 0; hc < 8; ++hc) {
    const int h0 = hc * 64;
    __syncthreads();   // previous ltile/ldsW consumers done
    #pragma unroll
    for (int it = 0; it < 4; ++it) {
      int idx = (it*256 + tid) * 8;
      int r = idx >> 7, c = idx & 127;
      float4 fa = *(const float4*)&w1[(size_t)(h0 + r)*Bdim + c];
      float4 fb = *(const float4*)&w1[(size_t)(h0 + r)*Bdim + c + 4];
      *(short8*)&ldsW[r*136 + c] = pack8(fa, fb);
    }
    __syncthreads();

    floatx4 acc[4] = {};
    #pragma unroll
    for (int ks = 0; ks < 4; ++ks) {
      #pragma unroll
      for (int nt = 0; nt < 4; ++nt) {
        short8 bfr = *(const short8*)&ldsW[(nt*16 + l16)*136 + ks*32 + quad*8];
        acc[nt] = __builtin_amdgcn_mfma_f32_16x16x32_bf16(afr[ks], bfr, acc[nt], 0, 0, 0);
      }
    }

    #pragma unroll
    for (int nt = 0; nt < 4; ++nt) {
      int hl = nt*16 + l16;                 // C/D: col = lane&15
      #pragma unroll
      for (int r = 0; r < 4; ++r) {
        int tl = wv*16 + quad*4 + r;        // C/D: row = quad*4+reg
        float v = acc[nt][r];
        v = v >= 0.f ? v : a1 * v;
        if (t0 + tl < Tdim) { lsum += v; lss += v*v; }
        ltile[tl*72 + hl] = f2bits(v);
      }
    }
    __syncthreads();
    {
      int tr2 = tid >> 2, ck = (tid & 3) * 16;
      int tg = t0 + tr2;
      if (tg < Tdim) {
        unsigned short* dst = &Hbuf[((size_t)m*Tdim + tg)*Hdim + h0 + ck];
        *(short8*)&dst[0] = *(const short8*)&ltile[tr2*72 + ck];
        *(short8*)&dst[8] = *(const short8*)&ltile[tr2*72 + ck + 8];
      }
    }
  }

  red[tid] = lsum; red[256 + tid] = lss;
  __syncthreads();
  for (int s = 128; s > 0; s >>= 1) {
    if (tid < s) { red[tid] += red[tid + s]; red[256+tid] += red[256+tid+s]; }
    __syncthreads();
  }
  if (tid == 0)
    part1[(size_t)m*63 + blockIdx.x] = make_float2(red[0], red[256]);
}

// ---------------- K2: fused offsets + deformable dw conv + PReLU2 + gLN2 partials -> Ybuf [M,T,H] bf16
// One wave per (m,t): computes the offset branch for its t (butterfly reduce over 512 ch),
// then the deformable gather/combine. gLN1 stats reduced inline from part1.
__global__ __launch_bounds__(256) void k_deform(
    const unsigned short* __restrict__ Hbuf,
    const float2* __restrict__ part1,
    const float* __restrict__ g1w,
    const float* __restrict__ b1w,
    const float* __restrict__ odw,
    const float* __restrict__ aodcp,
    const float* __restrict__ opw,
    const float* __restrict__ aopcp,
    const float* __restrict__ dww,
    const float* __restrict__ dwb,
    const float* __restrict__ a2p,
    unsigned short* __restrict__ Ybuf,
    float2* __restrict__ part2)
{
  __shared__ float s_stats[2];
  __shared__ float rsum[4], rss[4];
  const int tid = threadIdx.x, lane = tid & 63, w = tid >> 6;
  const int t = blockIdx.x*4 + w;          // grid.x = 1000
  const int m = blockIdx.y;

  // inline reduce of part1 -> stats1
  if (tid < 64) {
    float2 p = (lane < 63) ? part1[(size_t)m*63 + lane] : make_float2(0.f, 0.f);
    float s = p.x, q = p.y;
    #pragma unroll
    for (int st = 32; st > 0; st >>= 1) { s += __shfl_xor(s, st); q += __shfl_xor(q, st); }
    if (lane == 0) { s_stats[0] = s; s_stats[1] = q; }
  }
  __syncthreads();
  const float invn = 1.0f/(float)NPER;
  const float mean1 = s_stats[0]*invn;
  const float var1  = fmaxf(s_stats[1]*invn - mean1*mean1, 0.f);
  const float inv1  = 1.0f/sqrtf(var1 + EPSG);

  const int c8 = lane*8;
  const unsigned short* base = Hbuf + (size_t)m*Tdim*Hdim;

  float g1v[8], b1v[8];
  #pragma unroll
  for (int j = 0; j < 8; j += 4) {
    *(float4*)&g1v[j] = *(const float4*)&g1w[c8 + j];
    *(float4*)&b1v[j] = *(const float4*)&b1w[c8 + j];
  }

  // ---- offset branch for this t ----
  float o0 = 0.f, o1 = 0.f, o2 = 0.f;
  {
    const float aodc = aodcp[0];
    float wod[24], q0v[8], q1v[8], q2v[8];
    #pragma unroll
    for (int j = 0; j < 8; j += 4) {
      *(float4*)&q0v[j] = *(const float4*)&opw[c8 + j];
      *(float4*)&q1v[j] = *(const float4*)&opw[Hdim + c8 + j];
      *(float4*)&q2v[j] = *(const float4*)&opw[2*Hdim + c8 + j];
    }
    #pragma unroll
    for (int j = 0; j < 24; j += 4)
      *(float4*)&wod[j] = *(const float4*)&odw[c8*3 + j];

    const int tm1 = (t == 0) ? 1 : t-1;
    const int tp1 = (t == Tdim-1) ? Tdim-2 : t+1;
    short8 hm = *(const short8*)&base[(size_t)tm1*Hdim + c8];
    short8 hz = *(const short8*)&base[(size_t)t  *Hdim + c8];
    short8 hp = *(const short8*)&base[(size_t)tp1*Hdim + c8];

    #pragma unroll
    for (int j = 0; j < 8; ++j) {
      float A = g1v[j] * inv1;
      float C = b1v[j] - mean1*A;
      float fm = fmaf(A, bits2f((unsigned short)hm[j]), C);
      float fz = fmaf(A, bits2f((unsigned short)hz[j]), C);
      float fp = fmaf(A, bits2f((unsigned short)hp[j]), C);
      float d = fm*wod[j*3+0] + fz*wod[j*3+1] + fp*wod[j*3+2];
      d = d >= 0.f ? d : aodc*d;
      o0 = fmaf(d, q0v[j], o0);
      o1 = fmaf(d, q1v[j], o1);
      o2 = fmaf(d, q2v[j], o2);
    }
    #pragma unroll
    for (int s = 32; s > 0; s >>= 1) {
      o0 += __shfl_xor(o0, s);
      o1 += __shfl_xor(o1, s);
      o2 += __shfl_xor(o2, s);
    }
  }

  // ---- tap params (wave-uniform) ----
  const float aopc = aopcp[0];
  const float a2   = a2p[0];
  int I0[3], I1[3]; float G0[3], G1[3], GS[3];
  {
    const float tf = (float)t;
    float offs[3] = {o0, o1, o2};
    #pragma unroll
    for (int k = 0; k < 3; ++k) {
      float off = offs[k];
      off = off >= 0.f ? off : aopc*off;
      float pos = tf + (float)(2*k) + off;
      pos = fminf(fmaxf(pos, tf), tf + 4.0f);
      int U = (int)floorf(pos);
      if (U > Tdim + 2) U = Tdim + 2;        // Lp-2
      float Uf = (float)U;
      G0[k] = fmaxf(0.f, 1.f - fabsf(Uf - pos));
      G1[k] = fmaxf(0.f, 1.f - fabsf(Uf + 1.f - pos));
      GS[k] = G0[k] + G1[k];
      int ia = U - 2; ia = ia < 0 ? -ia : ia; if (ia > Tdim-1) ia = 2*(Tdim-1) - ia;
      int ib = U - 1; ib = ib < 0 ? -ib : ib; if (ib > Tdim-1) ib = 2*(Tdim-1) - ib;
      I0[k] = ia; I1[k] = ib;
    }
  }

  // ---- gather + combine ----
  short8 s0v[3], s1v[3];
  #pragma unroll
  for (int k = 0; k < 3; ++k) {
    s0v[k] = *(const short8*)&base[(size_t)I0[k]*Hdim + c8];
    s1v[k] = *(const short8*)&base[(size_t)I1[k]*Hdim + c8];
  }

  float bv[8], wd[24];
  #pragma unroll
  for (int j = 0; j < 8; j += 4)
    *(float4*)&bv[j] = *(const float4*)&dwb[c8 + j];
  #pragma unroll
  for (int j = 0; j < 24; j += 4)
    *(float4*)&wd[j] = *(const float4*)&dww[c8*3 + j];

  float lsum = 0.f, lss = 0.f;
  short8 yv;
  #pragma unroll
  for (int j = 0; j < 8; ++j) {
    float A = g1v[j] * inv1;
    float C = b1v[j] - mean1*A;
    float w0 = wd[j*3+0], w1 = wd[j*3+1], w2 = wd[j*3+2];
    float ybase = fmaf(C, w0*GS[0] + w1*GS[1] + w2*GS[2], bv[j]);
    float t0s = fmaf(G1[0], bits2f((unsigned short)s1v[0][j]), G0[0]*bits2f((unsigned short)s0v[0][j]));
    float t1s = fmaf(G1[1], bits2f((unsigned short)s1v[1][j]), G0[1]*bits2f((unsigned short)s0v[1][j]));
    float t2s = fmaf(G1[2], bits2f((unsigned short)s1v[2][j]), G0[2]*bits2f((unsigned short)s0v[2][j]));
    float acc = w0*t0s + w1*t1s + w2*t2s;
    float y = fmaf(A, acc, ybase);
    float p = y >= 0.f ? y : a2*y;
    lsum += p; lss += p*p;
    yv[j] = (short)f2bits(p);
  }
  *(short8*)&Ybuf[((size_t)m*Tdim + t)*Hdim + c8] = yv;

  #pragma unroll
  for (int s = 32; s > 0; s >>= 1) {
    lsum += __shfl_xor(lsum, s);
    lss  += __shfl_xor(lss, s);
  }
  if (lane == 0) { rsum[w] = lsum; rss[w] = lss; }
  __syncthreads();
  if (tid == 0)
    part2[(size_t)m*1000 + blockIdx.x] =
      make_float2(rsum[0]+rsum[1]+rsum[2]+rsum[3], rss[0]+rss[1]+rss[2]+rss[3]);
}

// ---------------- K3: reduce part2 + fold gLN2 into pointwise weights: W2 = A2*pw (bf16), const2 = sum C2*pw
__global__ __launch_bounds__(64) void k_w2(
    const float2* __restrict__ part2,
    const float* __restrict__ g2w,
    const float* __restrict__ b2w,
    const float* __restrict__ pww,
    unsigned short* __restrict__ W2,
    float* __restrict__ const2)
{
  const int bid = blockIdx.x;
  const int m = bid >> 7, b = bid & 127;
  const int tid = threadIdx.x;

  float s = 0.f, q = 0.f;
  for (int i = tid; i < 1000; i += 64) {
    float2 p = part2[(size_t)m*1000 + i];
    s += p.x; q += p.y;
  }
  #pragma unroll
  for (int st = 32; st > 0; st >>= 1) { s += __shfl_xor(s, st); q += __shfl_xor(q, st); }

  const float invn = 1.0f/(float)NPER;
  const float mean2 = s*invn;
  const float var2  = fmaxf(q*invn - mean2*mean2, 0.f);
  const float inv2  = 1.0f/sqrtf(var2 + EPSG);

  const int j8 = tid*8;
  float g2v[8], b2v[8], pv[8];
  #pragma unroll
  for (int j = 0; j < 8; j += 4) {
    *(float4*)&g2v[j] = *(const float4*)&g2w[j8 + j];
    *(float4*)&b2v[j] = *(const float4*)&b2w[j8 + j];
    *(float4*)&pv[j]  = *(const float4*)&pww[(size_t)b*Hdim + j8 + j];
  }
  float csum = 0.f;
  short8 wv8;
  #pragma unroll
  for (int j = 0; j < 8; ++j) {
    float A = g2v[j] * inv2;
    float C = b2v[j] - mean2*A;
    csum = fmaf(C, pv[j], csum);
    wv8[j] = (short)f2bits(A*pv[j]);
  }
  *(short8*)&W2[((size_t)m*Bdim + b)*Hdim + j8] = wv8;

  #pragma unroll
  for (int st = 32; st > 0; st >>= 1) csum += __shfl_down(csum, st);
  if (tid == 0) const2[m*Bdim + b] = csum;
}

// ---------------- K4: final GEMM Ybuf @ W2^T + const2 + residual -> out f32
__global__ __launch_bounds__(256) void k_out(
    const unsigned short* __restrict__ Ybuf,
    const unsigned short* __restrict__ W2,
    const float* __restrict__ const2,
    const float* __restrict__ x,
    float* __restrict__ out)
{
  __shared__ __align__(16) unsigned short ldsW[64*136];
  __shared__ __align__(16) float ltf[64*68];
  const int tid = threadIdx.x;
  const int t0 = blockIdx.x*64;
  const int n0 = blockIdx.y*64;
  const int m  = blockIdx.z;
  const int lane = tid & 63, wv = tid >> 6, quad = lane >> 4, l16 = lane & 15;
  int tr = t0 + wv*16 + l16;
  int trc = tr < Tdim ? tr : Tdim-1;
  const unsigned short* arow = Ybuf + ((size_t)m*Tdim + trc)*Hdim;
  floatx4 acc[4] = {};
  for (int kc = 0; kc < 4; ++kc) {
    __syncthreads();
    #pragma unroll
    for (int it = 0; it < 4; ++it) {
      int idx = (it*256 + tid)*8;
      int r = idx >> 7, c = idx & 127;
      *(short8*)&ldsW[r*136 + c] =
        *(const short8*)&W2[((size_t)m*Bdim + n0 + r)*Hdim + kc*128 + c];
    }
    __syncthreads();
    #pragma unroll
    for (int ks = 0; ks < 4; ++ks) {
      short8 afr = *(const short8*)&arow[kc*128 + ks*32 + quad*8];
      #pragma unroll
      for (int nt = 0; nt < 4; ++nt) {
        short8 bfr = *(const short8*)&ldsW[(nt*16 + l16)*136 + ks*32 + quad*8];
        acc[nt] = __builtin_amdgcn_mfma_f32_16x16x32_bf16(afr, bfr, acc[nt], 0, 0, 0);
      }
    }
  }
  __syncthreads();   // ldsW reuse done; now fill transpose tile
  #pragma unroll
  for (int nt = 0; nt < 4; ++nt) {
    int bl = nt*16 + l16;
    float cb = const2[m*Bdim + n0 + bl];
    #pragma unroll
    for (int r = 0; r < 4; ++r) {
      int tl = wv*16 + quad*4 + r;
      ltf[tl*68 + bl] = acc[nt][r] + cb;
    }
  }
  __syncthreads();
  {
    int tr2 = tid >> 2, ck = (tid & 3) * 16;
    int tg = t0 + tr2;
    if (tg < Tdim) {
      const float* xr = &x[((size_t)m*Tdim + tg)*Bdim + n0 + ck];
      float* orow = &out[((size_t)m*Tdim + tg)*Bdim + n0 + ck];
      #pragma unroll
      for (int j = 0; j < 4; ++j) {
        float4 v = *(const float4*)&ltf[tr2*68 + ck + j*4];
        float4 rx = *(const float4*)&xr[j*4];
        v.x += rx.x; v.y += rx.y; v.z += rx.z; v.w += rx.w;
        *(float4*)&orow[j*4] = v;
      }
    }
  }
}

extern "C" void kernel_launch(void* const* d_in, const int* in_sizes, int n_in,
                              void* d_out, int out_size, void* d_ws, size_t ws_size,
                              hipStream_t stream)
{
  (void)in_sizes; (void)n_in; (void)out_size; (void)ws_size;
  const float* x    = (const float*)d_in[0];
  const float* w1   = (const float*)d_in[1];
  const float* a1   = (const float*)d_in[2];
  const float* g1   = (const float*)d_in[3];
  const float* b1   = (const float*)d_in[4];
  const float* odw  = (const float*)d_in[5];
  const float* aodc = (const float*)d_in[6];
  const float* opw  = (const float*)d_in[7];
  const float* aopc = (const float*)d_in[8];
  const float* dww  = (const float*)d_in[9];
  const float* dwb  = (const float*)d_in[10];
  const float* a2   = (const float*)d_in[11];
  const float* g2   = (const float*)d_in[12];
  const float* b2   = (const float*)d_in[13];
  const float* pww  = (const float*)d_in[14];
  float* out = (float*)d_out;

  char* ws = (char*)d_ws;
  const size_t OFF_P1 = 0;          // part1 [M,63] float2: 4032 B
  const size_t OFF_C2 = 4096;       // const2 [M,B] f32: 4096 B
  const size_t OFF_P2 = 8192;       // part2 [M,1000] float2: 64000 B
  const size_t OFF_W2 = 72192;      // W2 [M,B,H] bf16: 1048576 B
  const size_t OFF_H  = 1120768;    // Hbuf [M,T,H] bf16: 32768000 B
  const size_t OFF_Y  = 33888768;   // Ybuf [M,T,H] bf16: 32768000 B
  float2* part1  = (float2*)(ws + OFF_P1);
  float*  const2 = (float*)(ws + OFF_C2);
  float2* part2  = (float2*)(ws + OFF_P2);
  unsigned short* W2   = (unsigned short*)(ws + OFF_W2);
  unsigned short* Hbuf = (unsigned short*)(ws + OFF_H);
  unsigned short* Ybuf = (unsigned short*)(ws + OFF_Y);

  k_conv1 <<<dim3(63, 8), 256, 0, stream>>>(x, w1, a1, Hbuf, part1);
  k_deform<<<dim3(1000, 8), 256, 0, stream>>>(Hbuf, part1, g1, b1, odw, aodc, opw, aopc, dww, dwb, a2, Ybuf, part2);
  k_w2    <<<dim3(1024), 64, 0, stream>>>(part2, g2, b2, pww, W2, const2);
  k_out   <<<dim3(63, 2, 8), 256, 0, stream>>>(Ybuf, W2, const2, x, out);
}

// Round 7
// 164.062 us; speedup vs baseline: 2.7700x; 1.0880x over previous
//
#include <hip/hip_runtime.h>

#define Mdim 8
#define Tdim 4000
#define Bdim 128
#define Hdim 512
#define NPER (Tdim*Hdim)
#define EPSG 1e-8f

typedef __attribute__((ext_vector_type(8))) short short8;
typedef __attribute__((ext_vector_type(4))) float floatx4;

static __device__ __forceinline__ float bits2f(unsigned short s) {
  union { unsigned int u; float f; } v; v.u = ((unsigned int)s) << 16; return v.f;
}
static __device__ __forceinline__ unsigned short f2bits(float f) {
  union { float f; unsigned int u; } v; v.f = f;
  unsigned int u = v.u;
  u += 0x7fffu + ((u >> 16) & 1u);   // RNE
  return (unsigned short)(u >> 16);
}
static __device__ __forceinline__ short8 pack8(const float4& a, const float4& b) {
  short8 v;
  v[0]=(short)f2bits(a.x); v[1]=(short)f2bits(a.y); v[2]=(short)f2bits(a.z); v[3]=(short)f2bits(a.w);
  v[4]=(short)f2bits(b.x); v[5]=(short)f2bits(b.y); v[6]=(short)f2bits(b.z); v[7]=(short)f2bits(b.w);
  return v;
}

// ---------------- K1: conv1 GEMM (x f32 -> bf16 MFMA) + PReLU + gLN1 partials -> Hbuf [M,T,H] bf16
// grid (63 t-tiles, 2 h-halves, 8 m); each block loops 4 h-chunks, x tile packed once per block.
__global__ __launch_bounds__(256) void k_conv1(
    const float* __restrict__ x,
    const float* __restrict__ w1,
    const float* __restrict__ a1p,
    unsigned short* __restrict__ Hbuf,
    float2* __restrict__ part1)
{
  __shared__ __align__(16) unsigned short ldsW[64*136];
  __shared__ __align__(16) unsigned short ltile[64*72];
  __shared__ float red[512];

  const int tid = threadIdx.x;
  const int t0 = blockIdx.x * 64;
  const int hh = blockIdx.y;         // h-half
  const int m  = blockIdx.z;

  const int lane = tid & 63, wv = tid >> 6, quad = lane >> 4, l16 = lane & 15;
  int tr = t0 + wv*16 + l16;
  int trc = tr < Tdim ? tr : Tdim-1;
  const float* xrow = x + ((size_t)m*Tdim + trc)*Bdim;
  short8 afr[4];
  #pragma unroll
  for (int ks = 0; ks < 4; ++ks) {
    float4 fa = *(const float4*)&xrow[ks*32 + quad*8];
    float4 fb = *(const float4*)&xrow[ks*32 + quad*8 + 4];
    afr[ks] = pack8(fa, fb);
  }

  const float a1 = a1p[0];
  float lsum = 0.f, lss = 0.f;

  for (int hc = 0; hc < 4; ++hc) {
    const int h0 = (hh*4 + hc) * 64;
    __syncthreads();   // previous ltile/ldsW consumers done
    #pragma unroll
    for (int it = 0; it < 4; ++it) {
      int idx = (it*256 + tid) * 8;
      int r = idx >> 7, c = idx & 127;
      float4 fa = *(const float4*)&w1[(size_t)(h0 + r)*Bdim + c];
      float4 fb = *(const float4*)&w1[(size_t)(h0 + r)*Bdim + c + 4];
      *(short8*)&ldsW[r*136 + c] = pack8(fa, fb);
    }
    __syncthreads();

    floatx4 acc[4] = {};
    #pragma unroll
    for (int ks = 0; ks < 4; ++ks) {
      #pragma unroll
      for (int nt = 0; nt < 4; ++nt) {
        short8 bfr = *(const short8*)&ldsW[(nt*16 + l16)*136 + ks*32 + quad*8];
        acc[nt] = __builtin_amdgcn_mfma_f32_16x16x32_bf16(afr[ks], bfr, acc[nt], 0, 0, 0);
      }
    }

    #pragma unroll
    for (int nt = 0; nt < 4; ++nt) {
      int hl = nt*16 + l16;                 // C/D: col = lane&15
      #pragma unroll
      for (int r = 0; r < 4; ++r) {
        int tl = wv*16 + quad*4 + r;        // C/D: row = quad*4+reg
        float v = acc[nt][r];
        v = v >= 0.f ? v : a1 * v;
        if (t0 + tl < Tdim) { lsum += v; lss += v*v; }
        ltile[tl*72 + hl] = f2bits(v);
      }
    }
    __syncthreads();
    {
      int tr2 = tid >> 2, ck = (tid & 3) * 16;
      int tg = t0 + tr2;
      if (tg < Tdim) {
        unsigned short* dst = &Hbuf[((size_t)m*Tdim + tg)*Hdim + h0 + ck];
        *(short8*)&dst[0] = *(const short8*)&ltile[tr2*72 + ck];
        *(short8*)&dst[8] = *(const short8*)&ltile[tr2*72 + ck + 8];
      }
    }
  }

  red[tid] = lsum; red[256 + tid] = lss;
  __syncthreads();
  for (int s = 128; s > 0; s >>= 1) {
    if (tid < s) { red[tid] += red[tid + s]; red[256+tid] += red[256+tid+s]; }
    __syncthreads();
  }
  if (tid == 0)
    part1[((size_t)m*2 + hh)*63 + blockIdx.x] = make_float2(red[0], red[256]);
}

// ---------------- K2: fused offsets + deformable dw conv + PReLU2 + gLN2 partials -> Ybuf [M,T,H] bf16
// One wave per (m, 2 consecutive t): offsets via butterfly reduce, then gathers. 2-t ILP.
__global__ __launch_bounds__(256) void k_deform(
    const unsigned short* __restrict__ Hbuf,
    const float2* __restrict__ part1,
    const float* __restrict__ g1w,
    const float* __restrict__ b1w,
    const float* __restrict__ odw,
    const float* __restrict__ aodcp,
    const float* __restrict__ opw,
    const float* __restrict__ aopcp,
    const float* __restrict__ dww,
    const float* __restrict__ dwb,
    const float* __restrict__ a2p,
    unsigned short* __restrict__ Ybuf,
    float2* __restrict__ part2)
{
  __shared__ float s_stats[2];
  __shared__ float rsum[4], rss[4];
  const int tid = threadIdx.x, lane = tid & 63, w = tid >> 6;
  const int tb = blockIdx.x*8 + w*2;       // grid.x = 500; wave handles t = tb, tb+1
  const int m = blockIdx.y;
  const int c8 = lane*8;
  const unsigned short* base = Hbuf + (size_t)m*Tdim*Hdim;

  // issue offset-branch row loads EARLY (independent of stats barrier)
  short8 hrow[2][3];
  #pragma unroll
  for (int tt = 0; tt < 2; ++tt) {
    int t = tb + tt;
    int tm1 = (t == 0) ? 1 : t-1;
    int tp1 = (t == Tdim-1) ? Tdim-2 : t+1;
    hrow[tt][0] = *(const short8*)&base[(size_t)tm1*Hdim + c8];
    hrow[tt][1] = *(const short8*)&base[(size_t)t  *Hdim + c8];
    hrow[tt][2] = *(const short8*)&base[(size_t)tp1*Hdim + c8];
  }
  float g1v[8], b1v[8];
  #pragma unroll
  for (int j = 0; j < 8; j += 4) {
    *(float4*)&g1v[j] = *(const float4*)&g1w[c8 + j];
    *(float4*)&b1v[j] = *(const float4*)&b1w[c8 + j];
  }

  // inline reduce of part1 (126 entries) -> stats1
  if (tid < 64) {
    float s = 0.f, q = 0.f;
    for (int i = lane; i < 126; i += 64) {
      float2 p = part1[(size_t)m*126 + i];
      s += p.x; q += p.y;
    }
    #pragma unroll
    for (int st = 32; st > 0; st >>= 1) { s += __shfl_xor(s, st); q += __shfl_xor(q, st); }
    if (lane == 0) { s_stats[0] = s; s_stats[1] = q; }
  }
  __syncthreads();
  const float invn = 1.0f/(float)NPER;
  const float mean1 = s_stats[0]*invn;
  const float var1  = fmaxf(s_stats[1]*invn - mean1*mean1, 0.f);
  const float inv1  = 1.0f/sqrtf(var1 + EPSG);

  // ---- offset branch for both t ----
  float oa[2][3] = {};
  {
    const float aodc = aodcp[0];
    float wod[24], q0v[8], q1v[8], q2v[8];
    #pragma unroll
    for (int j = 0; j < 8; j += 4) {
      *(float4*)&q0v[j] = *(const float4*)&opw[c8 + j];
      *(float4*)&q1v[j] = *(const float4*)&opw[Hdim + c8 + j];
      *(float4*)&q2v[j] = *(const float4*)&opw[2*Hdim + c8 + j];
    }
    #pragma unroll
    for (int j = 0; j < 24; j += 4)
      *(float4*)&wod[j] = *(const float4*)&odw[c8*3 + j];

    #pragma unroll
    for (int j = 0; j < 8; ++j) {
      float A = g1v[j] * inv1;
      float C = b1v[j] - mean1*A;
      #pragma unroll
      for (int tt = 0; tt < 2; ++tt) {
        float fm = fmaf(A, bits2f((unsigned short)hrow[tt][0][j]), C);
        float fz = fmaf(A, bits2f((unsigned short)hrow[tt][1][j]), C);
        float fp = fmaf(A, bits2f((unsigned short)hrow[tt][2][j]), C);
        float d = fm*wod[j*3+0] + fz*wod[j*3+1] + fp*wod[j*3+2];
        d = d >= 0.f ? d : aodc*d;
        oa[tt][0] = fmaf(d, q0v[j], oa[tt][0]);
        oa[tt][1] = fmaf(d, q1v[j], oa[tt][1]);
        oa[tt][2] = fmaf(d, q2v[j], oa[tt][2]);
      }
    }
    #pragma unroll
    for (int s = 32; s > 0; s >>= 1) {
      #pragma unroll
      for (int tt = 0; tt < 2; ++tt) {
        oa[tt][0] += __shfl_xor(oa[tt][0], s);
        oa[tt][1] += __shfl_xor(oa[tt][1], s);
        oa[tt][2] += __shfl_xor(oa[tt][2], s);
      }
    }
  }

  // ---- tap params (wave-uniform) + gathers for both t ----
  const float aopc = aopcp[0];
  const float a2   = a2p[0];
  int I0[2][3], I1[2][3]; float G0[2][3], G1[2][3], GS[2][3];
  #pragma unroll
  for (int tt = 0; tt < 2; ++tt) {
    const float tf = (float)(tb + tt);
    #pragma unroll
    for (int k = 0; k < 3; ++k) {
      float off = oa[tt][k];
      off = off >= 0.f ? off : aopc*off;
      float pos = tf + (float)(2*k) + off;
      pos = fminf(fmaxf(pos, tf), tf + 4.0f);
      int U = (int)floorf(pos);
      if (U > Tdim + 2) U = Tdim + 2;        // Lp-2
      float Uf = (float)U;
      G0[tt][k] = fmaxf(0.f, 1.f - fabsf(Uf - pos));
      G1[tt][k] = fmaxf(0.f, 1.f - fabsf(Uf + 1.f - pos));
      GS[tt][k] = G0[tt][k] + G1[tt][k];
      int ia = U - 2; ia = ia < 0 ? -ia : ia; if (ia > Tdim-1) ia = 2*(Tdim-1) - ia;
      int ib = U - 1; ib = ib < 0 ? -ib : ib; if (ib > Tdim-1) ib = 2*(Tdim-1) - ib;
      I0[tt][k] = ia; I1[tt][k] = ib;
    }
  }

  // issue ALL 12 gather loads up front (both t's) for maximum MLP
  short8 s0v[2][3], s1v[2][3];
  #pragma unroll
  for (int tt = 0; tt < 2; ++tt)
    #pragma unroll
    for (int k = 0; k < 3; ++k) {
      s0v[tt][k] = *(const short8*)&base[(size_t)I0[tt][k]*Hdim + c8];
      s1v[tt][k] = *(const short8*)&base[(size_t)I1[tt][k]*Hdim + c8];
    }

  float bv[8], wd[24];
  #pragma unroll
  for (int j = 0; j < 8; j += 4)
    *(float4*)&bv[j] = *(const float4*)&dwb[c8 + j];
  #pragma unroll
  for (int j = 0; j < 24; j += 4)
    *(float4*)&wd[j] = *(const float4*)&dww[c8*3 + j];

  float lsum = 0.f, lss = 0.f;
  short8 yv[2];
  #pragma unroll
  for (int j = 0; j < 8; ++j) {
    float A = g1v[j] * inv1;
    float C = b1v[j] - mean1*A;
    float w0 = wd[j*3+0], w1 = wd[j*3+1], w2 = wd[j*3+2];
    #pragma unroll
    for (int tt = 0; tt < 2; ++tt) {
      float ybase = fmaf(C, w0*GS[tt][0] + w1*GS[tt][1] + w2*GS[tt][2], bv[j]);
      float t0s = fmaf(G1[tt][0], bits2f((unsigned short)s1v[tt][0][j]), G0[tt][0]*bits2f((unsigned short)s0v[tt][0][j]));
      float t1s = fmaf(G1[tt][1], bits2f((unsigned short)s1v[tt][1][j]), G0[tt][1]*bits2f((unsigned short)s0v[tt][1][j]));
      float t2s = fmaf(G1[tt][2], bits2f((unsigned short)s1v[tt][2][j]), G0[tt][2]*bits2f((unsigned short)s0v[tt][2][j]));
      float acc = w0*t0s + w1*t1s + w2*t2s;
      float y = fmaf(A, acc, ybase);
      float p = y >= 0.f ? y : a2*y;
      lsum += p; lss += p*p;
      yv[tt][j] = (short)f2bits(p);
    }
  }
  #pragma unroll
  for (int tt = 0; tt < 2; ++tt)
    *(short8*)&Ybuf[((size_t)m*Tdim + tb + tt)*Hdim + c8] = yv[tt];

  #pragma unroll
  for (int s = 32; s > 0; s >>= 1) {
    lsum += __shfl_xor(lsum, s);
    lss  += __shfl_xor(lss, s);
  }
  if (lane == 0) { rsum[w] = lsum; rss[w] = lss; }
  __syncthreads();
  if (tid == 0)
    part2[(size_t)m*500 + blockIdx.x] =
      make_float2(rsum[0]+rsum[1]+rsum[2]+rsum[3], rss[0]+rss[1]+rss[2]+rss[3]);
}

// ---------------- K3: reduce part2 + fold gLN2 into pointwise weights: W2 = A2*pw (bf16), const2 = sum C2*pw
__global__ __launch_bounds__(64) void k_w2(
    const float2* __restrict__ part2,
    const float* __restrict__ g2w,
    const float* __restrict__ b2w,
    const float* __restrict__ pww,
    unsigned short* __restrict__ W2,
    float* __restrict__ const2)
{
  const int bid = blockIdx.x;
  const int m = bid >> 7, b = bid & 127;
  const int tid = threadIdx.x;

  float s = 0.f, q = 0.f;
  for (int i = tid; i < 500; i += 64) {
    float2 p = part2[(size_t)m*500 + i];
    s += p.x; q += p.y;
  }
  #pragma unroll
  for (int st = 32; st > 0; st >>= 1) { s += __shfl_xor(s, st); q += __shfl_xor(q, st); }

  const float invn = 1.0f/(float)NPER;
  const float mean2 = s*invn;
  const float var2  = fmaxf(q*invn - mean2*mean2, 0.f);
  const float inv2  = 1.0f/sqrtf(var2 + EPSG);

  const int j8 = tid*8;
  float g2v[8], b2v[8], pv[8];
  #pragma unroll
  for (int j = 0; j < 8; j += 4) {
    *(float4*)&g2v[j] = *(const float4*)&g2w[j8 + j];
    *(float4*)&b2v[j] = *(const float4*)&b2w[j8 + j];
    *(float4*)&pv[j]  = *(const float4*)&pww[(size_t)b*Hdim + j8 + j];
  }
  float csum = 0.f;
  short8 wv8;
  #pragma unroll
  for (int j = 0; j < 8; ++j) {
    float A = g2v[j] * inv2;
    float C = b2v[j] - mean2*A;
    csum = fmaf(C, pv[j], csum);
    wv8[j] = (short)f2bits(A*pv[j]);
  }
  *(short8*)&W2[((size_t)m*Bdim + b)*Hdim + j8] = wv8;

  #pragma unroll
  for (int st = 32; st > 0; st >>= 1) csum += __shfl_down(csum, st);
  if (tid == 0) const2[m*Bdim + b] = csum;
}

// ---------------- K4: final GEMM Ybuf @ W2^T + const2 + residual -> out f32
__global__ __launch_bounds__(256) void k_out(
    const unsigned short* __restrict__ Ybuf,
    const unsigned short* __restrict__ W2,
    const float* __restrict__ const2,
    const float* __restrict__ x,
    float* __restrict__ out)
{
  __shared__ __align__(16) unsigned short ldsW[64*136];
  __shared__ __align__(16) float ltf[64*68];
  const int tid = threadIdx.x;
  const int t0 = blockIdx.x*64;
  const int n0 = blockIdx.y*64;
  const int m  = blockIdx.z;
  const int lane = tid & 63, wv = tid >> 6, quad = lane >> 4, l16 = lane & 15;
  int tr = t0 + wv*16 + l16;
  int trc = tr < Tdim ? tr : Tdim-1;
  const unsigned short* arow = Ybuf + ((size_t)m*Tdim + trc)*Hdim;
  floatx4 acc[4] = {};
  for (int kc = 0; kc < 4; ++kc) {
    __syncthreads();
    #pragma unroll
    for (int it = 0; it < 4; ++it) {
      int idx = (it*256 + tid)*8;
      int r = idx >> 7, c = idx & 127;
      *(short8*)&ldsW[r*136 + c] =
        *(const short8*)&W2[((size_t)m*Bdim + n0 + r)*Hdim + kc*128 + c];
    }
    __syncthreads();
    #pragma unroll
    for (int ks = 0; ks < 4; ++ks) {
      short8 afr = *(const short8*)&arow[kc*128 + ks*32 + quad*8];
      #pragma unroll
      for (int nt = 0; nt < 4; ++nt) {
        short8 bfr = *(const short8*)&ldsW[(nt*16 + l16)*136 + ks*32 + quad*8];
        acc[nt] = __builtin_amdgcn_mfma_f32_16x16x32_bf16(afr, bfr, acc[nt], 0, 0, 0);
      }
    }
  }
  __syncthreads();   // ldsW reuse done; now fill transpose tile
  #pragma unroll
  for (int nt = 0; nt < 4; ++nt) {
    int bl = nt*16 + l16;
    float cb = const2[m*Bdim + n0 + bl];
    #pragma unroll
    for (int r = 0; r < 4; ++r) {
      int tl = wv*16 + quad*4 + r;
      ltf[tl*68 + bl] = acc[nt][r] + cb;
    }
  }
  __syncthreads();
  {
    int tr2 = tid >> 2, ck = (tid & 3) * 16;
    int tg = t0 + tr2;
    if (tg < Tdim) {
      const float* xr = &x[((size_t)m*Tdim + tg)*Bdim + n0 + ck];
      float* orow = &out[((size_t)m*Tdim + tg)*Bdim + n0 + ck];
      #pragma unroll
      for (int j = 0; j < 4; ++j) {
        float4 v = *(const float4*)&ltf[tr2*68 + ck + j*4];
        float4 rx = *(const float4*)&xr[j*4];
        v.x += rx.x; v.y += rx.y; v.z += rx.z; v.w += rx.w;
        *(float4*)&orow[j*4] = v;
      }
    }
  }
}

extern "C" void kernel_launch(void* const* d_in, const int* in_sizes, int n_in,
                              void* d_out, int out_size, void* d_ws, size_t ws_size,
                              hipStream_t stream)
{
  (void)in_sizes; (void)n_in; (void)out_size; (void)ws_size;
  const float* x    = (const float*)d_in[0];
  const float* w1   = (const float*)d_in[1];
  const float* a1   = (const float*)d_in[2];
  const float* g1   = (const float*)d_in[3];
  const float* b1   = (const float*)d_in[4];
  const float* odw  = (const float*)d_in[5];
  const float* aodc = (const float*)d_in[6];
  const float* opw  = (const float*)d_in[7];
  const float* aopc = (const float*)d_in[8];
  const float* dww  = (const float*)d_in[9];
  const float* dwb  = (const float*)d_in[10];
  const float* a2   = (const float*)d_in[11];
  const float* g2   = (const float*)d_in[12];
  const float* b2   = (const float*)d_in[13];
  const float* pww  = (const float*)d_in[14];
  float* out = (float*)d_out;

  char* ws = (char*)d_ws;
  const size_t OFF_P1 = 0;          // part1 [M,126] float2: 8064 B
  const size_t OFF_C2 = 8192;       // const2 [M,B] f32: 4096 B
  const size_t OFF_P2 = 12288;      // part2 [M,500] float2: 32000 B
  const size_t OFF_W2 = 44288;      // W2 [M,B,H] bf16: 1048576 B
  const size_t OFF_H  = 1092864;    // Hbuf [M,T,H] bf16: 32768000 B
  const size_t OFF_Y  = 33860864;   // Ybuf [M,T,H] bf16: 32768000 B
  float2* part1  = (float2*)(ws + OFF_P1);
  float*  const2 = (float*)(ws + OFF_C2);
  float2* part2  = (float2*)(ws + OFF_P2);
  unsigned short* W2   = (unsigned short*)(ws + OFF_W2);
  unsigned short* Hbuf = (unsigned short*)(ws + OFF_H);
  unsigned short* Ybuf = (unsigned short*)(ws + OFF_Y);

  k_conv1 <<<dim3(63, 2, 8), 256, 0, stream>>>(x, w1, a1, Hbuf, part1);
  k_deform<<<dim3(500, 8), 256, 0, stream>>>(Hbuf, part1, g1, b1, odw, aodc, opw, aopc, dww, dwb, a2, Ybuf, part2);
  k_w2    <<<dim3(1024), 64, 0, stream>>>(part2, g2, b2, pww, W2, const2);
  k_out   <<<dim3(63, 2, 8), 256, 0, stream>>>(Ybuf, W2, const2, x, out);
}